// Round 3
// baseline (174.919 us; speedup 1.0000x reference)
//
#include <hip/hip_runtime.h>
#include <math.h>

// Problem constants (from reference setup_inputs)
#define BATCH 512
#define LEN   16384
#define WIN   5
#define WOUT  (LEN - WIN + 1)   // 16380
#define TPB   256
#define WPT   4                  // windows per thread (WOUT % WPT == 0)
#define WPB   (TPB * WPT)        // 1024 windows per block
#define EPT   (WPT + WIN - 1)    // 8 elements per thread
#define NCH2  8                  // stage-A output chunk groups

// fast reciprocal: v_rcp_f32 + 1 Newton step, ~3 insts vs ~10 for fdiv
__device__ __forceinline__ float fast_rcp(float x) {
    float r = __builtin_amdgcn_rcpf(x);
    return r * fmaf(-x, r, 2.0f);
}

// One batch-row's worth of per-thread inputs: 8 elements (halo included).
// 8 x 16B vector loads = 128 B/thread, all coalesced.
struct Row {
    int4   m0, m1, t0, t1;
    float4 q0, q1, q2, q3;
};

__device__ __forceinline__ Row load_row(const float* __restrict__ pred,
                                        const int*   __restrict__ tgt,
                                        const int*   __restrict__ msk,
                                        size_t base) {
    Row r;
    r.m0 = *(const int4*)(msk + base);
    r.m1 = *(const int4*)(msk + base + 4);
    r.t0 = *(const int4*)(tgt + base);
    r.t1 = *(const int4*)(tgt + base + 4);
    r.q0 = *(const float4*)(pred + base * 2);
    r.q1 = *(const float4*)(pred + base * 2 + 4);
    r.q2 = *(const float4*)(pred + base * 2 + 8);
    r.q3 = *(const float4*)(pred + base * 2 + 12);
    return r;
}

// Same arithmetic & tap order as the verified kernel -> bit-identical partials.
__device__ __forceinline__ void accum_row(const Row& r,
                                          float accd2[WPT], float accms[WPT]) {
    float m[EPT], tm[EPT], pm[EPT], p2m[EPT];
    {
        const int mi[EPT] = {r.m0.x, r.m0.y, r.m0.z, r.m0.w,
                             r.m1.x, r.m1.y, r.m1.z, r.m1.w};
        const int ti[EPT] = {r.t0.x, r.t0.y, r.t0.z, r.t0.w,
                             r.t1.x, r.t1.y, r.t1.z, r.t1.w};
        const float dx[EPT] = {r.q0.x - r.q0.y, r.q0.z - r.q0.w,
                               r.q1.x - r.q1.y, r.q1.z - r.q1.w,
                               r.q2.x - r.q2.y, r.q2.z - r.q2.w,
                               r.q3.x - r.q3.y, r.q3.z - r.q3.w};
#pragma unroll
        for (int i = 0; i < EPT; ++i) {
            const float p  = fast_rcp(1.0f + __expf(dx[i]));  // softmax[...,1]
            const float mf = (float)mi[i];
            m[i]   = mf;
            tm[i]  = (float)(ti[i] & mi[i]);  // t*m, both in {0,1}
            pm[i]  = p * mf;
            p2m[i] = p * p * mf;
        }
    }
#pragma unroll
    for (int w = 0; w < WPT; ++w) {
        float msum = 0.f, stm = 0.f, spm = 0.f, sp2m = 0.f;
#pragma unroll
        for (int k = 0; k < WIN; ++k) {   // ascending tap order (kept)
            msum += m[w + k];
            stm  += tm[w + k];
            spm  += pm[w + k];
            sp2m += p2m[w + k];
        }
        // st2m == stm since t in {0,1}
        const float denom = fmaxf(msum, 1.0f);
        const float inv   = fast_rcp(denom);
        const float pmean = spm * inv;
        const float tmean = stm * inv;
        const float pvar  = (sp2m - 2.0f * pmean * spm + pmean * pmean * msum) * inv;
        const float tvar  = (stm  - 2.0f * tmean * stm + tmean * tmean * msum) * inv;
        const float d = pvar - tvar;
        accd2[w] += d * d;
        accms[w] += msum;
    }
}

// Kernel 1: register sliding-window with explicit 2-deep software pipeline
// over the batch loop. Loads for row b+1 issue BEFORE compute on row b, so
// HBM latency hides under compute x 4 waves/SIMD. launch_bounds(256,4)
// gives a 128-VGPR budget: two Row buffers (64) + temps fit without spill.
__global__ __launch_bounds__(TPB, 4)
void bcl_partial_kernel(const float* __restrict__ pred,
                        const int*   __restrict__ tgt,
                        const int*   __restrict__ msk,
                        float* __restrict__ part_d2,
                        float* __restrict__ part_ms,
                        int bper) {
    const int j0 = blockIdx.x * WPB + (int)threadIdx.x * WPT;  // first window
    if (j0 >= WOUT) return;     // only last block's last thread exits
    const int b0 = blockIdx.y * bper;

    float accd2[WPT] = {0.f, 0.f, 0.f, 0.f};
    float accms[WPT] = {0.f, 0.f, 0.f, 0.f};

    size_t base = (size_t)b0 * LEN + j0;  // j0 % 4 == 0 -> 16B aligned

    // prologue: load row b0
    Row A = load_row(pred, tgt, msk, base);

    // steady state: process pairs (A,B), prefetching 1 row ahead of compute.
    // bper is even (512/nchunks, nchunks <= 256 power of 2).
    for (int it = 0; it + 2 < bper; it += 2) {
        Row B = load_row(pred, tgt, msk, base + LEN);      // prefetch b+1
        accum_row(A, accd2, accms);                        // compute b
        A = load_row(pred, tgt, msk, base + 2 * (size_t)LEN); // prefetch b+2
        accum_row(B, accd2, accms);                        // compute b+1
        base += 2 * (size_t)LEN;
    }
    // epilogue: last pair (A holds row bper-2)
    {
        Row B = load_row(pred, tgt, msk, base + LEN);
        accum_row(A, accd2, accms);
        accum_row(B, accd2, accms);
    }

    // coalesced float4 stores (WOUT % 4 == 0 keeps rows 16B aligned)
    *(float4*)(part_d2 + (size_t)blockIdx.y * WOUT + j0) =
        make_float4(accd2[0], accd2[1], accd2[2], accd2[3]);
    *(float4*)(part_ms + (size_t)blockIdx.y * WOUT + j0) =
        make_float4(accms[0], accms[1], accms[2], accms[3]);
}

// Stage A: fold nchunks -> NCH2 chunk groups with real TLP (grid.y = NCH2).
// Also zeroes the accumulators/ticket (replaces the hipMemsetAsync enqueue;
// stream order guarantees stage A completes before stage B starts).
__global__ __launch_bounds__(TPB)
void bcl_chunk_reduce(const float* __restrict__ part_d2,
                      const float* __restrict__ part_ms,
                      float* __restrict__ p2_d2,
                      float* __restrict__ p2_ms,
                      double* __restrict__ accum,
                      unsigned int* __restrict__ ticket,
                      int rf) {
    if (blockIdx.x == 0 && blockIdx.y == 0 && threadIdx.x == 0) {
        accum[0] = 0.0; accum[1] = 0.0; *ticket = 0u;
    }
    const int j = blockIdx.x * blockDim.x + threadIdx.x;
    if (j >= WOUT) return;
    const int c0 = blockIdx.y * rf;
    float d2 = 0.f, ms = 0.f;
#pragma unroll 8
    for (int c = c0; c < c0 + rf; ++c) {   // ascending c: deterministic
        d2 += part_d2[(size_t)c * WOUT + j];
        ms += part_ms[(size_t)c * WOUT + j];
    }
    p2_d2[(size_t)blockIdx.y * WOUT + j] = d2;
    p2_ms[(size_t)blockIdx.y * WOUT + j] = ms;
}

// Stage B: fold NCH2 groups -> mse*valid; block-reduce to doubles; atomicAdd
// into global accumulators; last block finalizes output.
__global__ __launch_bounds__(TPB)
void bcl_window_reduce(const float* __restrict__ p2_d2,
                       const float* __restrict__ p2_ms,
                       double* __restrict__ accum,  // [num, cnt]
                       unsigned int* __restrict__ ticket,
                       float* __restrict__ out,
                       int nch2) {
    const int j = blockIdx.x * blockDim.x + threadIdx.x;
    double num = 0.0, cnt = 0.0;
    if (j < WOUT) {
        float d2 = 0.f, ms = 0.f;
#pragma unroll 8
        for (int c = 0; c < nch2; ++c) {   // ascending group order
            d2 += p2_d2[(size_t)c * WOUT + j];
            ms += p2_ms[(size_t)c * WOUT + j];
        }
        if (ms > 0.f) {
            num = (double)d2 * (1.0 / (double)BATCH);
            cnt = 1.0;
        }
    }
    // wave reduce (wave = 64)
    for (int off = 32; off > 0; off >>= 1) {
        num += __shfl_down(num, off, 64);
        cnt += __shfl_down(cnt, off, 64);
    }
    __shared__ double s_num[4], s_cnt[4];
    const int lane = threadIdx.x & 63, wave = threadIdx.x >> 6;
    if (lane == 0) { s_num[wave] = num; s_cnt[wave] = cnt; }
    __syncthreads();
    if (threadIdx.x == 0) {
        double n = 0.0, c = 0.0;
        const int nw = (int)(blockDim.x >> 6);
        for (int wv = 0; wv < nw; ++wv) { n += s_num[wv]; c += s_cnt[wv]; }
        atomicAdd(&accum[0], n);
        atomicAdd(&accum[1], c);
        __threadfence();
        const unsigned int t = atomicAdd(ticket, 1u);
        if (t == gridDim.x - 1) {
            out[0] = (float)(accum[0] / fmax(accum[1], 1.0));
        }
    }
}

extern "C" void kernel_launch(void* const* d_in, const int* in_sizes, int n_in,
                              void* d_out, int out_size, void* d_ws, size_t ws_size,
                              hipStream_t stream) {
    const float* pred = (const float*)d_in[0];
    const int*   tgt  = (const int*)d_in[1];
    const int*   msk  = (const int*)d_in[2];
    float* out = (float*)d_out;

    // Largest batch-chunk count that fits in workspace (divides 512, pow2).
    int nchunks = 64;
    while (nchunks > 2) {
        size_t need = (size_t)(nchunks + NCH2) * WOUT * 2 * sizeof(float) + 256;
        if (need <= ws_size) break;
        nchunks >>= 1;
    }
    const int bper = BATCH / nchunks;          // even for nchunks <= 256
    const int nch2 = (nchunks >= NCH2) ? NCH2 : nchunks;
    const int rf   = nchunks / nch2;

    float* part_d2 = (float*)d_ws;
    float* part_ms = part_d2 + (size_t)nchunks * WOUT;
    float* p2_d2   = part_ms + (size_t)nchunks * WOUT;
    float* p2_ms   = p2_d2   + (size_t)NCH2 * WOUT;
    // 16-byte-aligned tail region: [double num, double cnt, uint ticket]
    size_t off = ((size_t)((char*)(p2_ms + (size_t)NCH2 * WOUT) - (char*)d_ws) + 15) & ~(size_t)15;
    double* accum = (double*)((char*)d_ws + off);
    unsigned int* ticket = (unsigned int*)(accum + 2);

    const int WBLKS = (WOUT + WPB - 1) / WPB;  // 16
    dim3 g1(WBLKS, nchunks);
    bcl_partial_kernel<<<g1, TPB, 0, stream>>>(pred, tgt, msk, part_d2, part_ms, bper);

    const int RBLKS = (WOUT + TPB - 1) / TPB;  // 64
    dim3 gA(RBLKS, nch2);
    bcl_chunk_reduce<<<gA, TPB, 0, stream>>>(part_d2, part_ms, p2_d2, p2_ms,
                                             accum, ticket, rf);

    bcl_window_reduce<<<RBLKS, TPB, 0, stream>>>(p2_d2, p2_ms, accum, ticket, out, nch2);
}

// Round 4
// 164.692 us; speedup vs baseline: 1.0621x; 1.0621x over previous
//
#include <hip/hip_runtime.h>
#include <math.h>

// Problem constants (from reference setup_inputs)
#define BATCH 512
#define LEN   16384
#define WIN   5
#define WOUT  (LEN - WIN + 1)   // 16380
#define TPB   256
#define WPT   4                  // windows per thread (WOUT % WPT == 0)
#define WPB   (TPB * WPT)        // 1024 windows per block
#define EPT   (WPT + WIN - 1)    // 8 elements per thread
#define NCH2  16                 // stage-A output chunk groups

// fast reciprocal: v_rcp_f32 + 1 Newton step, ~3 insts vs ~10 for fdiv
__device__ __forceinline__ float fast_rcp(float x) {
    float r = __builtin_amdgcn_rcpf(x);
    return r * fmaf(-x, r, 2.0f);
}

// Raw vector loads for one batch row: 8 x 16B, 32 VGPRs.
struct RowRaw {
    int4   m0, m1, t0, t1;
    float4 q0, q1, q2, q3;
};

// Converted per-element quantities: 32 VGPRs.
struct RowArr {
    float m[EPT], tm[EPT], pm[EPT], p2m[EPT];
};

__device__ __forceinline__ RowRaw load_row(const float* __restrict__ pred,
                                           const int*   __restrict__ tgt,
                                           const int*   __restrict__ msk,
                                           size_t base) {
    RowRaw r;
    r.m0 = *(const int4*)(msk + base);
    r.m1 = *(const int4*)(msk + base + 4);
    r.t0 = *(const int4*)(tgt + base);
    r.t1 = *(const int4*)(tgt + base + 4);
    r.q0 = *(const float4*)(pred + base * 2);
    r.q1 = *(const float4*)(pred + base * 2 + 4);
    r.q2 = *(const float4*)(pred + base * 2 + 8);
    r.q3 = *(const float4*)(pred + base * 2 + 12);
    return r;
}

// Same per-element arithmetic as the verified round-2 kernel.
__device__ __forceinline__ RowArr convert_row(const RowRaw& r) {
    RowArr a;
    const int mi[EPT] = {r.m0.x, r.m0.y, r.m0.z, r.m0.w,
                         r.m1.x, r.m1.y, r.m1.z, r.m1.w};
    const int ti[EPT] = {r.t0.x, r.t0.y, r.t0.z, r.t0.w,
                         r.t1.x, r.t1.y, r.t1.z, r.t1.w};
    const float dx[EPT] = {r.q0.x - r.q0.y, r.q0.z - r.q0.w,
                           r.q1.x - r.q1.y, r.q1.z - r.q1.w,
                           r.q2.x - r.q2.y, r.q2.z - r.q2.w,
                           r.q3.x - r.q3.y, r.q3.z - r.q3.w};
#pragma unroll
    for (int i = 0; i < EPT; ++i) {
        const float p  = fast_rcp(1.0f + __expf(dx[i]));  // softmax[...,1]
        const float mf = (float)mi[i];
        a.m[i]   = mf;
        a.tm[i]  = (float)(ti[i] & mi[i]);  // t*m, both in {0,1}
        a.pm[i]  = p * mf;
        a.p2m[i] = p * p * mf;
    }
    return a;
}

// Same window math & ascending tap order -> bit-identical partials.
__device__ __forceinline__ void windows_row(const RowArr& a,
                                            float accd2[WPT], float accms[WPT]) {
#pragma unroll
    for (int w = 0; w < WPT; ++w) {
        float msum = 0.f, stm = 0.f, spm = 0.f, sp2m = 0.f;
#pragma unroll
        for (int k = 0; k < WIN; ++k) {
            msum += a.m[w + k];
            stm  += a.tm[w + k];
            spm  += a.pm[w + k];
            sp2m += a.p2m[w + k];
        }
        // st2m == stm since t in {0,1}
        const float denom = fmaxf(msum, 1.0f);
        const float inv   = fast_rcp(denom);
        const float pmean = spm * inv;
        const float tmean = stm * inv;
        const float pvar  = (sp2m - 2.0f * pmean * spm + pmean * pmean * msum) * inv;
        const float tvar  = (stm  - 2.0f * tmean * stm + tmean * tmean * msum) * inv;
        const float d = pvar - tvar;
        accd2[w] += d * d;
        accms[w] += msum;
    }
}

// Kernel 1: register sliding-window, software-pipelined at the ARRAY level:
// one raw buffer (32 regs) + one converted buffer (32 regs). Row b+1's loads
// are issued before row b's window compute, consumed after -> one exposed
// latency per row instead of ~4. No launch_bounds min-waves clause: the
// allocator is free (round 3's forced 2xRow variant spilled ~52 MB to
// scratch at VGPR=64; this fits in ~96).
__global__ __launch_bounds__(TPB)
void bcl_partial_kernel(const float* __restrict__ pred,
                        const int*   __restrict__ tgt,
                        const int*   __restrict__ msk,
                        float* __restrict__ part_d2,
                        float* __restrict__ part_ms,
                        int bper) {
    const int j0 = blockIdx.x * WPB + (int)threadIdx.x * WPT;  // first window
    if (j0 >= WOUT) return;     // only last block's tail threads exit
    const int b0 = blockIdx.y * bper;

    float accd2[WPT] = {0.f, 0.f, 0.f, 0.f};
    float accms[WPT] = {0.f, 0.f, 0.f, 0.f};

    size_t base = (size_t)b0 * LEN + j0;  // j0 % 4 == 0 -> 16B aligned

    // prologue: row b0 loaded and converted
    RowRaw raw = load_row(pred, tgt, msk, base);
    RowArr arr = convert_row(raw);

    for (int it = 1; it < bper; ++it) {
        raw = load_row(pred, tgt, msk, base + (size_t)it * LEN);  // prefetch b0+it
        windows_row(arr, accd2, accms);                           // compute b0+it-1
        arr = convert_row(raw);                                   // consume prefetch
    }
    windows_row(arr, accd2, accms);                               // last row

    // coalesced float4 stores (WOUT % 4 == 0 keeps rows 16B aligned)
    *(float4*)(part_d2 + (size_t)blockIdx.y * WOUT + j0) =
        make_float4(accd2[0], accd2[1], accd2[2], accd2[3]);
    *(float4*)(part_ms + (size_t)blockIdx.y * WOUT + j0) =
        make_float4(accms[0], accms[1], accms[2], accms[3]);
}

// Stage A: fold nchunks -> NCH2 chunk groups with real TLP (grid.y = NCH2).
// Also zeroes the accumulators/ticket (stream order protects stage B).
__global__ __launch_bounds__(TPB)
void bcl_chunk_reduce(const float* __restrict__ part_d2,
                      const float* __restrict__ part_ms,
                      float* __restrict__ p2_d2,
                      float* __restrict__ p2_ms,
                      double* __restrict__ accum,
                      unsigned int* __restrict__ ticket,
                      int rf) {
    if (blockIdx.x == 0 && blockIdx.y == 0 && threadIdx.x == 0) {
        accum[0] = 0.0; accum[1] = 0.0; *ticket = 0u;
    }
    const int j = blockIdx.x * blockDim.x + threadIdx.x;
    if (j >= WOUT) return;
    const int c0 = blockIdx.y * rf;
    float d2 = 0.f, ms = 0.f;
#pragma unroll 8
    for (int c = c0; c < c0 + rf; ++c) {   // ascending c: deterministic
        d2 += part_d2[(size_t)c * WOUT + j];
        ms += part_ms[(size_t)c * WOUT + j];
    }
    p2_d2[(size_t)blockIdx.y * WOUT + j] = d2;
    p2_ms[(size_t)blockIdx.y * WOUT + j] = ms;
}

// Stage B: fold NCH2 groups -> mse*valid; block-reduce to doubles; atomicAdd
// into global accumulators; last block finalizes output.
__global__ __launch_bounds__(TPB)
void bcl_window_reduce(const float* __restrict__ p2_d2,
                       const float* __restrict__ p2_ms,
                       double* __restrict__ accum,  // [num, cnt]
                       unsigned int* __restrict__ ticket,
                       float* __restrict__ out,
                       int nch2) {
    const int j = blockIdx.x * blockDim.x + threadIdx.x;
    double num = 0.0, cnt = 0.0;
    if (j < WOUT) {
        float d2 = 0.f, ms = 0.f;
#pragma unroll 8
        for (int c = 0; c < nch2; ++c) {   // ascending group order
            d2 += p2_d2[(size_t)c * WOUT + j];
            ms += p2_ms[(size_t)c * WOUT + j];
        }
        if (ms > 0.f) {
            num = (double)d2 * (1.0 / (double)BATCH);
            cnt = 1.0;
        }
    }
    // wave reduce (wave = 64)
    for (int off = 32; off > 0; off >>= 1) {
        num += __shfl_down(num, off, 64);
        cnt += __shfl_down(cnt, off, 64);
    }
    __shared__ double s_num[4], s_cnt[4];
    const int lane = threadIdx.x & 63, wave = threadIdx.x >> 6;
    if (lane == 0) { s_num[wave] = num; s_cnt[wave] = cnt; }
    __syncthreads();
    if (threadIdx.x == 0) {
        double n = 0.0, c = 0.0;
        const int nw = (int)(blockDim.x >> 6);
        for (int wv = 0; wv < nw; ++wv) { n += s_num[wv]; c += s_cnt[wv]; }
        atomicAdd(&accum[0], n);
        atomicAdd(&accum[1], c);
        __threadfence();
        const unsigned int t = atomicAdd(ticket, 1u);
        if (t == gridDim.x - 1) {
            out[0] = (float)(accum[0] / fmax(accum[1], 1.0));
        }
    }
}

extern "C" void kernel_launch(void* const* d_in, const int* in_sizes, int n_in,
                              void* d_out, int out_size, void* d_ws, size_t ws_size,
                              hipStream_t stream) {
    const float* pred = (const float*)d_in[0];
    const int*   tgt  = (const int*)d_in[1];
    const int*   msk  = (const int*)d_in[2];
    float* out = (float*)d_out;

    // Largest batch-chunk count that fits in workspace (divides 512, pow2).
    int nchunks = 128;
    while (nchunks > 2) {
        size_t need = (size_t)(nchunks + NCH2) * WOUT * 2 * sizeof(float) + 256;
        if (need <= ws_size) break;
        nchunks >>= 1;
    }
    const int bper = BATCH / nchunks;
    const int nch2 = (nchunks >= NCH2) ? NCH2 : nchunks;
    const int rf   = nchunks / nch2;

    float* part_d2 = (float*)d_ws;
    float* part_ms = part_d2 + (size_t)nchunks * WOUT;
    float* p2_d2   = part_ms + (size_t)nchunks * WOUT;
    float* p2_ms   = p2_d2   + (size_t)NCH2 * WOUT;
    // 16-byte-aligned tail region: [double num, double cnt, uint ticket]
    size_t off = ((size_t)((char*)(p2_ms + (size_t)NCH2 * WOUT) - (char*)d_ws) + 15) & ~(size_t)15;
    double* accum = (double*)((char*)d_ws + off);
    unsigned int* ticket = (unsigned int*)(accum + 2);

    const int WBLKS = (WOUT + WPB - 1) / WPB;  // 16
    dim3 g1(WBLKS, nchunks);
    bcl_partial_kernel<<<g1, TPB, 0, stream>>>(pred, tgt, msk, part_d2, part_ms, bper);

    const int RBLKS = (WOUT + TPB - 1) / TPB;  // 64
    dim3 gA(RBLKS, nch2);
    bcl_chunk_reduce<<<gA, TPB, 0, stream>>>(part_d2, part_ms, p2_d2, p2_ms,
                                             accum, ticket, rf);

    bcl_window_reduce<<<RBLKS, TPB, 0, stream>>>(p2_d2, p2_ms, accum, ticket, out, nch2);
}